// Round 1
// baseline (392.561 us; speedup 1.0000x reference)
//
#include <hip/hip_runtime.h>
#include <hip/hip_bf16.h>

// Problem constants (fixed by the reference setup)
//   x: (B,T,I) fp32, W: (H,I) fp32, alpha: (H,), u0,s0: (B,H)
//   out: spikes (B,T,H) fp32
#define ALPHA_MIN 0.8187307530779818f  // exp(-1/5)
#define ALPHA_MAX 0.9607894391523232f  // exp(-1/25)

// ---------------- GEMM: C[M,N] = X[M,K] * W[N,K]^T (fp32, vector ALU) -------
// TILE 128x128, TK=16, 256 threads, 8x8 micro-tile per thread.
#define TM 128
#define TN 128
#define TK 16

__global__ __launch_bounds__(256) void gemm_xwT(
    const float* __restrict__ X,   // (M,K) row-major
    const float* __restrict__ W,   // (N,K) row-major
    float* __restrict__ C,         // (M,N) row-major
    int M, int N, int K)
{
    __shared__ float As[TK][TM];   // transposed: As[k][m]
    __shared__ float Bs[TK][TN];   // transposed: Bs[k][n]

    const int tid = threadIdx.x;
    const int m0 = blockIdx.x * TM;
    const int n0 = blockIdx.y * TN;

    const int tx = tid & 15;       // 0..15 -> n micro
    const int ty = tid >> 4;       // 0..15 -> m micro

    float acc[8][8];
#pragma unroll
    for (int i = 0; i < 8; ++i)
#pragma unroll
        for (int j = 0; j < 8; ++j) acc[i][j] = 0.0f;

    for (int k0 = 0; k0 < K; k0 += TK) {
        // ---- stage A tile: 128 rows x 16 k = 512 float4, 2 per thread ----
#pragma unroll
        for (int i = 0; i < 2; ++i) {
            int idx = tid * 2 + i;          // 0..511
            int row = idx >> 2;             // 0..127
            int c   = idx & 3;              // float4 column within k-tile
            float4 v = *(const float4*)&X[(size_t)(m0 + row) * K + k0 + c * 4];
            As[c * 4 + 0][row] = v.x;
            As[c * 4 + 1][row] = v.y;
            As[c * 4 + 2][row] = v.z;
            As[c * 4 + 3][row] = v.w;
        }
        // ---- stage B tile: 128 rows x 16 k ----
#pragma unroll
        for (int i = 0; i < 2; ++i) {
            int idx = tid * 2 + i;
            int row = idx >> 2;
            int c   = idx & 3;
            float4 v = *(const float4*)&W[(size_t)(n0 + row) * K + k0 + c * 4];
            Bs[c * 4 + 0][row] = v.x;
            Bs[c * 4 + 1][row] = v.y;
            Bs[c * 4 + 2][row] = v.z;
            Bs[c * 4 + 3][row] = v.w;
        }
        __syncthreads();

        // ---- compute ----
#pragma unroll
        for (int k = 0; k < TK; ++k) {
            float4 a0 = *(const float4*)&As[k][ty * 4];
            float4 a1 = *(const float4*)&As[k][ty * 4 + 64];
            float4 b0 = *(const float4*)&Bs[k][tx * 4];
            float4 b1 = *(const float4*)&Bs[k][tx * 4 + 64];
            float av[8] = {a0.x, a0.y, a0.z, a0.w, a1.x, a1.y, a1.z, a1.w};
            float bv[8] = {b0.x, b0.y, b0.z, b0.w, b1.x, b1.y, b1.z, b1.w};
#pragma unroll
            for (int i = 0; i < 8; ++i)
#pragma unroll
                for (int j = 0; j < 8; ++j)
                    acc[i][j] = fmaf(av[i], bv[j], acc[i][j]);
        }
        __syncthreads();
    }

    // ---- epilogue: 16 float4 stores per thread ----
#pragma unroll
    for (int i = 0; i < 8; ++i) {
        int m = m0 + ((i < 4) ? (ty * 4 + i) : (64 + ty * 4 + (i - 4)));
        float4 v0 = {acc[i][0], acc[i][1], acc[i][2], acc[i][3]};
        float4 v1 = {acc[i][4], acc[i][5], acc[i][6], acc[i][7]};
        *(float4*)&C[(size_t)m * N + n0 + tx * 4]      = v0;
        *(float4*)&C[(size_t)m * N + n0 + 64 + tx * 4] = v1;
    }
}

// ---------------- LIF scan over T (in-place on d_out) -----------------------
// One thread per (b,h) chain; 64-thread blocks -> 256 single-wave blocks
// spread over 256 CUs. Unroll-32 prefetch for memory-latency hiding.
#define SCAN_U 32

__global__ __launch_bounds__(64) void lif_scan(
    float* __restrict__ buf,            // (B,T,H): in = Wx, out = spikes
    const float* __restrict__ alpha,
    const float* __restrict__ u0,
    const float* __restrict__ s0,
    int T, int H)
{
    const int chain = blockIdx.x * 64 + threadIdx.x;  // b*H + h
    const int h = chain & (H - 1);                    // H = 512 (pow2)
    const int b = chain >> 9;

    float a = alpha[h];
    a = fminf(fmaxf(a, ALPHA_MIN), ALPHA_MAX);
    const float bb = 1.0f - a;

    float u = u0[chain];
    float s = s0[chain];

    float* base = buf + (size_t)b * T * H + h;

    for (int t0 = 0; t0 < T; t0 += SCAN_U) {
        float w[SCAN_U];
#pragma unroll
        for (int j = 0; j < SCAN_U; ++j)
            w[j] = base[(size_t)(t0 + j) * H];
#pragma unroll
        for (int j = 0; j < SCAN_U; ++j) {
            u = a * (u - s) + bb * w[j];
            s = (u > 1.0f) ? 1.0f : 0.0f;
            base[(size_t)(t0 + j) * H] = s;
        }
    }
}

// ---------------- launch ----------------------------------------------------
extern "C" void kernel_launch(void* const* d_in, const int* in_sizes, int n_in,
                              void* d_out, int out_size, void* d_ws, size_t ws_size,
                              hipStream_t stream) {
    const float* x     = (const float*)d_in[0];
    const float* W     = (const float*)d_in[1];
    const float* alpha = (const float*)d_in[2];
    const float* u0    = (const float*)d_in[3];
    const float* s0    = (const float*)d_in[4];
    float* out = (float*)d_out;

    const int H = in_sizes[2];              // 512
    const int I = in_sizes[1] / H;          // 256
    const int B = in_sizes[3] / H;          // 32
    const int T = in_sizes[0] / (B * I);    // 2048
    const int M = B * T;                    // 65536

    // 1) Wx -> d_out  (M x H), fp32 GEMM
    dim3 grid(M / TM, H / TN);
    gemm_xwT<<<grid, 256, 0, stream>>>(x, W, out, M, H, I);

    // 2) in-place LIF scan over T
    lif_scan<<<(B * H) / 64, 64, 0, stream>>>(out, alpha, u0, s0, T, H);
}

// Round 2
// 302.867 us; speedup vs baseline: 1.2961x; 1.2961x over previous
//
#include <hip/hip_runtime.h>
#include <hip/hip_bf16.h>

#define ALPHA_MIN 0.8187307530779818f  // exp(-1/5)
#define ALPHA_MAX 0.9607894391523232f  // exp(-1/25)

typedef _Float16 f16;
typedef _Float16 f16x8 __attribute__((ext_vector_type(8)));
typedef float f32x16 __attribute__((ext_vector_type(16)));

// ---------------- GEMM: C[M,N] = X[M,K] * W[N,K]^T via fp16-split MFMA ------
// fp32 = hi(fp16) + lo(fp16)*2^-11;  C = Ah*Bh + 2^-11*(Ah*Bl' + Al'*Bh),
// where lo' = (x - hi)*2048 (kept normal-range, no denormal flush).
// Dropped term Al*Bl ~ 2^-22 relative. Error ~1e-6 absolute in Wx (std 1).
//
// Tile 128x128, BK=32, 256 threads = 4 waves, each wave 64x64 via 2x2 of
// v_mfma_f32_32x32x16_f16.  LDS rows: 32 data + 8 pad fp16 = 80 B
// (16B-aligned rows; bank-quad stride 20 ≡ odd*4 → conflict-minimal).
#define LDSTRIDE 40

__global__ __launch_bounds__(256, 2) void gemm_f16x3(
    const float* __restrict__ X,   // (M,K) row-major
    const float* __restrict__ W,   // (N,K) row-major
    float* __restrict__ C,         // (M,N) row-major
    int M, int N, int K)
{
    __shared__ f16 Ah[128 * LDSTRIDE];
    __shared__ f16 Al[128 * LDSTRIDE];
    __shared__ f16 Bh[128 * LDSTRIDE];
    __shared__ f16 Bl[128 * LDSTRIDE];

    const int tid = threadIdx.x;
    // swizzle: 4 consecutive blocks share one m-strip (x reuse in L2/L3)
    const int mt = blockIdx.x >> 2;
    const int nt = blockIdx.x & 3;
    const int m0 = mt * 128, n0 = nt * 128;

    const int lane = tid & 63;
    const int wv   = tid >> 6;
    const int wm   = wv & 1;       // wave m-half (0/1)
    const int wn   = wv >> 1;      // wave n-half (0/1)
    const int fm   = lane & 31;    // m (or n) within 32x32 frag
    const int fq   = lane >> 5;    // k-half selector

    // staging: thread -> (row, 8k-chunk); 2 outer iters cover 128 rows
    const int srow = tid >> 2;     // 0..63
    const int sc8  = tid & 3;      // 0..3

    f32x16 accH[2][2], accL[2][2];
#pragma unroll
    for (int i = 0; i < 2; ++i)
#pragma unroll
        for (int j = 0; j < 2; ++j)
#pragma unroll
            for (int e = 0; e < 16; ++e) { accH[i][j][e] = 0.0f; accL[i][j][e] = 0.0f; }

    const int KT = K / 32;
    for (int kt = 0; kt < KT; ++kt) {
        // ---- stage A,B: fp32 -> (hi, lo*2048) fp16 pairs in LDS ----
#pragma unroll
        for (int i = 0; i < 2; ++i) {
            const int row = srow + 64 * i;
            {
                const float* src = X + (size_t)(m0 + row) * K + kt * 32 + sc8 * 8;
                float4 v0 = *(const float4*)(src);
                float4 v1 = *(const float4*)(src + 4);
                float vin[8] = {v0.x, v0.y, v0.z, v0.w, v1.x, v1.y, v1.z, v1.w};
                f16x8 hv, lv;
#pragma unroll
                for (int j = 0; j < 8; ++j) {
                    f16 hj = (f16)vin[j];
                    hv[j] = hj;
                    lv[j] = (f16)((vin[j] - (float)hj) * 2048.0f);
                }
                *(f16x8*)&Ah[row * LDSTRIDE + sc8 * 8] = hv;
                *(f16x8*)&Al[row * LDSTRIDE + sc8 * 8] = lv;
            }
            {
                const float* src = W + (size_t)(n0 + row) * K + kt * 32 + sc8 * 8;
                float4 v0 = *(const float4*)(src);
                float4 v1 = *(const float4*)(src + 4);
                float vin[8] = {v0.x, v0.y, v0.z, v0.w, v1.x, v1.y, v1.z, v1.w};
                f16x8 hv, lv;
#pragma unroll
                for (int j = 0; j < 8; ++j) {
                    f16 hj = (f16)vin[j];
                    hv[j] = hj;
                    lv[j] = (f16)((vin[j] - (float)hj) * 2048.0f);
                }
                *(f16x8*)&Bh[row * LDSTRIDE + sc8 * 8] = hv;
                *(f16x8*)&Bl[row * LDSTRIDE + sc8 * 8] = lv;
            }
        }
        __syncthreads();

        // ---- compute: 2 kslices x (2x2 mfma tiles) x 3 passes ----
#pragma unroll
        for (int ks = 0; ks < 2; ++ks) {
            f16x8 af[2][2], bf[2][2];   // [block][hi/lo]
#pragma unroll
            for (int mb = 0; mb < 2; ++mb) {
                const int ro = (wm * 64 + mb * 32 + fm) * LDSTRIDE + ks * 16 + fq * 8;
                af[mb][0] = *(const f16x8*)&Ah[ro];
                af[mb][1] = *(const f16x8*)&Al[ro];
            }
#pragma unroll
            for (int nb = 0; nb < 2; ++nb) {
                const int ro = (wn * 64 + nb * 32 + fm) * LDSTRIDE + ks * 16 + fq * 8;
                bf[nb][0] = *(const f16x8*)&Bh[ro];
                bf[nb][1] = *(const f16x8*)&Bl[ro];
            }
#pragma unroll
            for (int mb = 0; mb < 2; ++mb)
#pragma unroll
                for (int nb = 0; nb < 2; ++nb) {
                    accH[mb][nb] = __builtin_amdgcn_mfma_f32_32x32x16_f16(af[mb][0], bf[nb][0], accH[mb][nb], 0, 0, 0);
                    accL[mb][nb] = __builtin_amdgcn_mfma_f32_32x32x16_f16(af[mb][0], bf[nb][1], accL[mb][nb], 0, 0, 0);
                    accL[mb][nb] = __builtin_amdgcn_mfma_f32_32x32x16_f16(af[mb][1], bf[nb][0], accL[mb][nb], 0, 0, 0);
                }
        }
        __syncthreads();
    }

    // ---- epilogue: C = accH + accL * 2^-11 ----
    // C/D layout (m74/m101): col = lane&31, row = (reg&3) + 8*(reg>>2) + 4*(lane>>5)
#pragma unroll
    for (int mb = 0; mb < 2; ++mb)
#pragma unroll
        for (int nb = 0; nb < 2; ++nb) {
            const int col   = n0 + wn * 64 + nb * 32 + fm;
            const int rbase = m0 + wm * 64 + mb * 32 + 4 * fq;
#pragma unroll
            for (int g = 0; g < 4; ++g)
#pragma unroll
                for (int r = 0; r < 4; ++r) {
                    const int row = rbase + 8 * g + r;
                    const float v = accH[mb][nb][4 * g + r]
                                  + accL[mb][nb][4 * g + r] * (1.0f / 2048.0f);
                    C[(size_t)row * N + col] = v;
                }
        }
}

// ---------------- LIF scan over T (in-place on d_out) -----------------------
// 1 thread per (b,h) chain, 256 single-wave blocks (1 wave/CU).
// Double-buffered prefetch: load chunk c+1 while computing chunk c.
#define SU 64

__global__ __launch_bounds__(64) void lif_scan(
    float* __restrict__ buf,            // (B,T,H): in = Wx, out = spikes
    const float* __restrict__ alpha,
    const float* __restrict__ u0,
    const float* __restrict__ s0,
    int T, int H)
{
    const int chain = blockIdx.x * 64 + threadIdx.x;  // b*H + h
    const int h = chain % H;
    const int b = chain / H;

    float a = alpha[h];
    a = fminf(fmaxf(a, ALPHA_MIN), ALPHA_MAX);
    const float bb = 1.0f - a;

    float u = u0[chain];
    float s = s0[chain];

    float* base = buf + (size_t)b * T * H + h;

    float w0[SU], w1[SU];
#pragma unroll
    for (int j = 0; j < SU; ++j) w0[j] = base[(size_t)j * H];

    const int NC = T / SU;                 // 32 (even)
    for (int c = 0; c < NC; c += 2) {
        // prefetch chunk c+1
#pragma unroll
        for (int j = 0; j < SU; ++j) w1[j] = base[(size_t)((c + 1) * SU + j) * H];
        // compute + store chunk c
#pragma unroll
        for (int j = 0; j < SU; ++j) {
            const float d = u - s;
            u = fmaf(a, d, bb * w0[j]);
            s = (u > 1.0f) ? 1.0f : 0.0f;
            base[(size_t)(c * SU + j) * H] = s;
        }
        // prefetch chunk c+2
        if (c + 2 < NC) {
#pragma unroll
            for (int j = 0; j < SU; ++j) w0[j] = base[(size_t)((c + 2) * SU + j) * H];
        }
        // compute + store chunk c+1
#pragma unroll
        for (int j = 0; j < SU; ++j) {
            const float d = u - s;
            u = fmaf(a, d, bb * w1[j]);
            s = (u > 1.0f) ? 1.0f : 0.0f;
            base[(size_t)((c + 1) * SU + j) * H] = s;
        }
    }
}

// ---------------- launch ----------------------------------------------------
extern "C" void kernel_launch(void* const* d_in, const int* in_sizes, int n_in,
                              void* d_out, int out_size, void* d_ws, size_t ws_size,
                              hipStream_t stream) {
    const float* x     = (const float*)d_in[0];
    const float* W     = (const float*)d_in[1];
    const float* alpha = (const float*)d_in[2];
    const float* u0    = (const float*)d_in[3];
    const float* s0    = (const float*)d_in[4];
    float* out = (float*)d_out;

    const int H = in_sizes[2];              // 512
    const int I = in_sizes[1] / H;          // 256
    const int B = in_sizes[3] / H;          // 32
    const int T = in_sizes[0] / (B * I);    // 2048
    const int M = B * T;                    // 65536

    // 1) Wx -> d_out  (M x H) via fp16-split MFMA
    const int grid = (M / 128) * (H / 128);
    gemm_f16x3<<<grid, 256, 0, stream>>>(x, W, out, M, H, I);

    // 2) in-place LIF scan over T
    lif_scan<<<(B * H) / 64, 64, 0, stream>>>(out, alpha, u0, s0, T, H);
}